// Round 1
// baseline (378.320 us; speedup 1.0000x reference)
//
#include <hip/hip_runtime.h>
#include <math.h>

#define NP 65536
#define NJ 16
#define WID 64
#define HH 64
#define NPOU 4
#define NSUB 2

__device__ __forceinline__ float fast_tanh(float x) {
    // tanh(x) = 1 - 2/(exp(2x)+1); handles +/-inf saturation correctly
    float e = __expf(2.0f * x);
    return 1.0f - 2.0f / (e + 1.0f);
}

// ---------------- POU network: w_all[j][p] = softmax_j(MLP(x)) ----------------
__global__ __launch_bounds__(256) void pou_kernel(
    const float* __restrict__ x,       // [P][2]
    const float* __restrict__ W0,      // [2][64]
    const float* __restrict__ b0,      // [64]
    const float* __restrict__ Wh,      // [4][64][64]
    const float* __restrict__ bh,      // [4][64]
    const float* __restrict__ Wl,      // [64][16]
    const float* __restrict__ bl,      // [16]
    float* __restrict__ w_all)         // [J][P]  (transposed for coalescing)
{
    __shared__ __align__(16) float sWh[NPOU][HH][HH];   // 64 KB
    __shared__ __align__(16) float sWl[HH][NJ];         // 4 KB
    __shared__ __align__(16) float sW0[2][HH];
    __shared__ float sb0[HH];
    __shared__ float sbh[NPOU][HH];
    __shared__ float sbl[NJ];

    const int tid = threadIdx.x;
    for (int i = tid; i < NPOU * HH * HH; i += 256) ((float*)sWh)[i] = Wh[i];
    for (int i = tid; i < HH * NJ; i += 256) ((float*)sWl)[i] = Wl[i];
    if (tid < 2 * HH) ((float*)sW0)[tid] = W0[tid];
    if (tid < HH) sb0[tid] = b0[tid];
    for (int i = tid; i < NPOU * HH; i += 256) ((float*)sbh)[i] = bh[i];
    if (tid < NJ) sbl[tid] = bl[tid];
    __syncthreads();

    const int p = blockIdx.x * 256 + tid;
    const float x0 = x[2 * p], x1 = x[2 * p + 1];

    float h[HH];
#pragma unroll
    for (int w = 0; w < HH; ++w)
        h[w] = fmaxf(x0 * sW0[0][w] + x1 * sW0[1][w] + sb0[w], 0.0f);

#pragma unroll 1
    for (int r = 0; r < NPOU; ++r) {
        const float* wrow = &sWh[r][0][0];
        const float* brow = &sbh[r][0];
        float acc[HH];
#pragma unroll
        for (int w = 0; w < HH; ++w) acc[w] = brow[w];
#pragma unroll
        for (int v = 0; v < HH; ++v) {
            const float hv = h[v];
#pragma unroll
            for (int w = 0; w < HH; ++w) acc[w] += hv * wrow[v * HH + w];
        }
#pragma unroll
        for (int w = 0; w < HH; ++w) h[w] += fmaxf(acc[w], 0.0f);
    }

    float lg[NJ];
#pragma unroll
    for (int j = 0; j < NJ; ++j) lg[j] = sbl[j];
#pragma unroll
    for (int w = 0; w < HH; ++w) {
        const float hw = h[w];
#pragma unroll
        for (int j = 0; j < NJ; ++j) lg[j] += hw * sWl[w][j];
    }

    float m = lg[0];
#pragma unroll
    for (int j = 1; j < NJ; ++j) m = fmaxf(m, lg[j]);
    float s = 0.0f;
#pragma unroll
    for (int j = 0; j < NJ; ++j) { lg[j] = __expf(lg[j] - m); s += lg[j]; }
    const float inv = 1.0f / s;
#pragma unroll
    for (int j = 0; j < NJ; ++j) w_all[j * NP + p] = lg[j] * inv;
}

// ------------- Subnet j over a point tile: upart[j][p] = w_all[j][p]*u_j(p) -------------
__global__ __launch_bounds__(256) void subnet_kernel(
    const float* __restrict__ x,        // [P][2]
    const float* __restrict__ gW0,      // [J][2][64]
    const float* __restrict__ gb0,      // [J][64]
    const float* __restrict__ gWh,      // [J][2][64][64]
    const float* __restrict__ gbh,      // [J][2][64]
    const float* __restrict__ gWl,      // [J][64]   (last dim 1 squeezed)
    const float* __restrict__ gbl,      // [J]
    const float* __restrict__ w_all,    // [J][P]
    float* __restrict__ upart)          // [J][P]
{
    const int j = blockIdx.y;
    __shared__ __align__(16) float sWh[NSUB][WID][WID];  // 32 KB
    __shared__ __align__(16) float sW0[2][WID];
    __shared__ float sb0[WID];
    __shared__ float sbh[NSUB][WID];
    __shared__ float sWl[WID];
    __shared__ float sbl1;

    const int tid = threadIdx.x;
    {
        const float* src = gWh + j * (NSUB * WID * WID);
        for (int i = tid; i < NSUB * WID * WID; i += 256) ((float*)sWh)[i] = src[i];
        if (tid < 2 * WID) ((float*)sW0)[tid] = gW0[j * 2 * WID + tid];
        if (tid < WID) sb0[tid] = gb0[j * WID + tid];
        if (tid < NSUB * WID) ((float*)sbh)[tid] = gbh[j * NSUB * WID + tid];
        if (tid < WID) sWl[tid] = gWl[j * WID + tid];
        if (tid == 0) sbl1 = gbl[j];
    }
    __syncthreads();

    const int p = blockIdx.x * 256 + tid;
    const float x0 = x[2 * p], x1 = x[2 * p + 1];
    const float xs0 = (x0 - 0.5f) * 2.0f;
    const float xs1 = (x1 - 0.5f) * 2.0f;

    float h[WID];
#pragma unroll
    for (int w = 0; w < WID; ++w)
        h[w] = fast_tanh(xs0 * sW0[0][w] + xs1 * sW0[1][w] + sb0[w]);

#pragma unroll 1
    for (int L = 0; L < NSUB; ++L) {
        const float* wrow = &sWh[L][0][0];
        const float* brow = &sbh[L][0];
        float acc[WID];
#pragma unroll
        for (int w = 0; w < WID; ++w) acc[w] = brow[w];
#pragma unroll
        for (int v = 0; v < WID; ++v) {
            const float hv = h[v];
#pragma unroll
            for (int w = 0; w < WID; ++w) acc[w] += hv * wrow[v * WID + w];
        }
#pragma unroll
        for (int w = 0; w < WID; ++w) h[w] = fast_tanh(acc[w]);
    }

    float u = sbl1;
#pragma unroll
    for (int w = 0; w < WID; ++w) u += h[w] * sWl[w];

    upart[j * NP + p] = u * w_all[j * NP + p];
}

// ---------------- Reduce over j + Dirichlet ansatz ----------------
__global__ __launch_bounds__(256) void reduce_kernel(
    const float* __restrict__ x,
    const float* __restrict__ upart,    // [J][P]
    float* __restrict__ out)            // [P]
{
    const int p = blockIdx.x * 256 + threadIdx.x;
    float s = 0.0f;
#pragma unroll
    for (int j = 0; j < NJ; ++j) s += upart[j * NP + p];
    const float x0 = x[2 * p], x1 = x[2 * p + 1];
    const float pi = 3.14159265358979323846f;
    out[p] = s * sinf(pi * x0) * sinf(pi * x1);
}

extern "C" void kernel_launch(void* const* d_in, const int* in_sizes, int n_in,
                              void* d_out, int out_size, void* d_ws, size_t ws_size,
                              hipStream_t stream) {
    const float* x      = (const float*)d_in[0];
    const float* sub_W0 = (const float*)d_in[1];
    const float* sub_b0 = (const float*)d_in[2];
    const float* sub_Wh = (const float*)d_in[3];
    const float* sub_bh = (const float*)d_in[4];
    const float* sub_Wl = (const float*)d_in[5];
    const float* sub_bl = (const float*)d_in[6];
    const float* pou_W0 = (const float*)d_in[7];
    const float* pou_b0 = (const float*)d_in[8];
    const float* pou_Wh = (const float*)d_in[9];
    const float* pou_bh = (const float*)d_in[10];
    const float* pou_Wl = (const float*)d_in[11];
    const float* pou_bl = (const float*)d_in[12];

    float* w_all = (float*)d_ws;                 // [J][P]  4 MB
    float* upart = (float*)d_ws + (size_t)NJ * NP; // [J][P]  4 MB

    pou_kernel<<<NP / 256, 256, 0, stream>>>(x, pou_W0, pou_b0, pou_Wh, pou_bh,
                                             pou_Wl, pou_bl, w_all);

    dim3 g2(NP / 256, NJ);
    subnet_kernel<<<g2, 256, 0, stream>>>(x, sub_W0, sub_b0, sub_Wh, sub_bh,
                                          sub_Wl, sub_bl, w_all, upart);

    reduce_kernel<<<NP / 256, 256, 0, stream>>>(x, upart, (float*)d_out);
}

// Round 2
// 154.923 us; speedup vs baseline: 2.4420x; 2.4420x over previous
//
#include <hip/hip_runtime.h>
#include <math.h>

#define NP 65536
#define NJ 16
#define WID 64
#define HH 64
#define NPOU 4
#define NSUB 2
#define LDA 72   // padded LDS row stride in bf16 elems: 144 B = 9*16 B (b128-aligned, conflict-floor)

typedef __attribute__((ext_vector_type(8))) short short8;
typedef __attribute__((ext_vector_type(4))) float f32x4;

__device__ __forceinline__ unsigned short f2bf(float f) {
    unsigned u = __float_as_uint(f);
    u += 0x7FFFu + ((u >> 16) & 1u);   // round-to-nearest-even
    return (unsigned short)(u >> 16);
}

__device__ __forceinline__ float fast_tanh(float x) {
    // tanh(x) = 1 - 2/(exp(2x)+1); saturates correctly at +/-inf
    float e = __expf(2.0f * x);
    float r = __builtin_amdgcn_rcpf(e + 1.0f);
    return fmaf(-2.0f, r, 1.0f);
}

// ---------------- POU network (unchanged from passing R1): w_all[j][p] ----------------
__global__ __launch_bounds__(256) void pou_kernel(
    const float* __restrict__ x,
    const float* __restrict__ W0, const float* __restrict__ b0,
    const float* __restrict__ Wh, const float* __restrict__ bh,
    const float* __restrict__ Wl, const float* __restrict__ bl,
    float* __restrict__ w_all)
{
    __shared__ __align__(16) float sWh[NPOU][HH][HH];
    __shared__ __align__(16) float sWl[HH][NJ];
    __shared__ __align__(16) float sW0[2][HH];
    __shared__ float sb0[HH];
    __shared__ float sbh[NPOU][HH];
    __shared__ float sbl[NJ];

    const int tid = threadIdx.x;
    for (int i = tid; i < NPOU * HH * HH; i += 256) ((float*)sWh)[i] = Wh[i];
    for (int i = tid; i < HH * NJ; i += 256) ((float*)sWl)[i] = Wl[i];
    if (tid < 2 * HH) ((float*)sW0)[tid] = W0[tid];
    if (tid < HH) sb0[tid] = b0[tid];
    for (int i = tid; i < NPOU * HH; i += 256) ((float*)sbh)[i] = bh[i];
    if (tid < NJ) sbl[tid] = bl[tid];
    __syncthreads();

    const int p = blockIdx.x * 256 + tid;
    const float x0 = x[2 * p], x1 = x[2 * p + 1];

    float h[HH];
#pragma unroll
    for (int w = 0; w < HH; ++w)
        h[w] = fmaxf(x0 * sW0[0][w] + x1 * sW0[1][w] + sb0[w], 0.0f);

#pragma unroll 1
    for (int r = 0; r < NPOU; ++r) {
        const float* wrow = &sWh[r][0][0];
        const float* brow = &sbh[r][0];
        float acc[HH];
#pragma unroll
        for (int w = 0; w < HH; ++w) acc[w] = brow[w];
#pragma unroll
        for (int v = 0; v < HH; ++v) {
            const float hv = h[v];
#pragma unroll
            for (int w = 0; w < HH; ++w) acc[w] += hv * wrow[v * HH + w];
        }
#pragma unroll
        for (int w = 0; w < HH; ++w) h[w] += fmaxf(acc[w], 0.0f);
    }

    float lg[NJ];
#pragma unroll
    for (int j = 0; j < NJ; ++j) lg[j] = sbl[j];
#pragma unroll
    for (int w = 0; w < HH; ++w) {
        const float hw = h[w];
#pragma unroll
        for (int j = 0; j < NJ; ++j) lg[j] += hw * sWl[w][j];
    }

    float m = lg[0];
#pragma unroll
    for (int j = 1; j < NJ; ++j) m = fmaxf(m, lg[j]);
    float s = 0.0f;
#pragma unroll
    for (int j = 0; j < NJ; ++j) { lg[j] = __expf(lg[j] - m); s += lg[j]; }
    const float inv = 1.0f / s;
#pragma unroll
    for (int j = 0; j < NJ; ++j) w_all[j * NP + p] = lg[j] * inv;
}

// ------------- MFMA subnet: block = 256 pts x one j; 4 waves, 64 pts/wave -------------
__global__ __launch_bounds__(256) void subnet_mfma_kernel(
    const float* __restrict__ x,
    const float* __restrict__ gW0, const float* __restrict__ gb0,
    const float* __restrict__ gWh, const float* __restrict__ gbh,
    const float* __restrict__ gWl, const float* __restrict__ gbl,
    const float* __restrict__ w_all,
    float* __restrict__ upart)
{
    __shared__ unsigned short sA[4 * 64 * LDA];        // per-wave activation tiles (bf16)
    __shared__ unsigned short sWt[NSUB * 64 * LDA];    // W^T per hidden layer (bf16): [n][k]
    __shared__ float sW0[2 * WID];
    __shared__ float sb0[WID];
    __shared__ float sbh[NSUB * WID];
    __shared__ float sWl[WID];

    const int tid  = threadIdx.x;
    const int j    = blockIdx.y;
    const int wave = tid >> 6;
    const int lane = tid & 63;
    const int r15  = lane & 15;
    const int g    = lane >> 4;

    // ---- stage weights (convert fp32 -> bf16, W transposed to [n][k]) ----
    {
        const float* src = gWh + j * (NSUB * WID * WID);
        for (int idx = tid; idx < NSUB * WID * WID; idx += 256) {
            int L = idx >> 12, rem = idx & 4095;
            int k = rem >> 6, n = rem & 63;
            sWt[L * 64 * LDA + n * LDA + k] = f2bf(src[idx]);
        }
        if (tid < 2 * WID)    sW0[tid] = gW0[j * 2 * WID + tid];
        if (tid < WID)        sb0[tid] = gb0[j * WID + tid];
        if (tid < NSUB * WID) sbh[tid] = gbh[j * NSUB * WID + tid];
        if (tid < WID)        sWl[tid] = gWl[j * WID + tid];
    }
    __syncthreads();

    const int pbase = blockIdx.x * 256;

    // ---- layer 0 (K=2): scalar per-thread, write bf16 row into this wave's sA tile ----
    {
        const int p = pbase + tid;
        float2 xv = ((const float2*)x)[p];
        float xs0 = (xv.x - 0.5f) * 2.0f, xs1 = (xv.y - 0.5f) * 2.0f;
        unsigned short* row = &sA[(wave * 64 + lane) * LDA];
#pragma unroll
        for (int c = 0; c < WID; c += 2) {
            float v0 = fast_tanh(fmaf(xs0, sW0[c],     fmaf(xs1, sW0[WID + c],     sb0[c])));
            float v1 = fast_tanh(fmaf(xs0, sW0[c + 1], fmaf(xs1, sW0[WID + c + 1], sb0[c + 1])));
            *(unsigned*)&row[c] = (unsigned)f2bf(v0) | ((unsigned)f2bf(v1) << 16);
        }
    }

    const unsigned short* myA = &sA[wave * 64 * LDA];
    f32x4 acc[4][4];

    // ---- hidden layers via MFMA: D = A(64x64) @ W(64x64) ----
#pragma unroll
    for (int L = 0; L < NSUB; ++L) {
        short8 bf[2][4];
#pragma unroll
        for (int kc = 0; kc < 2; ++kc)
#pragma unroll
            for (int nt = 0; nt < 4; ++nt)
                bf[kc][nt] = *(const short8*)&sWt[L * 64 * LDA + (nt * 16 + r15) * LDA + kc * 32 + g * 8];

#pragma unroll
        for (int mt = 0; mt < 4; ++mt)
#pragma unroll
            for (int nt = 0; nt < 4; ++nt) acc[mt][nt] = (f32x4)(0.0f);

#pragma unroll
        for (int mt = 0; mt < 4; ++mt) {
            short8 a0 = *(const short8*)&myA[(mt * 16 + r15) * LDA + 0 * 32 + g * 8];
            short8 a1 = *(const short8*)&myA[(mt * 16 + r15) * LDA + 1 * 32 + g * 8];
#pragma unroll
            for (int nt = 0; nt < 4; ++nt) {
                acc[mt][nt] = __builtin_amdgcn_mfma_f32_16x16x32_bf16(a0, bf[0][nt], acc[mt][nt], 0, 0, 0);
                acc[mt][nt] = __builtin_amdgcn_mfma_f32_16x16x32_bf16(a1, bf[1][nt], acc[mt][nt], 0, 0, 0);
            }
        }

        float bias[4];
#pragma unroll
        for (int nt = 0; nt < 4; ++nt) bias[nt] = sbh[L * WID + nt * 16 + r15];

#pragma unroll
        for (int mt = 0; mt < 4; ++mt)
#pragma unroll
            for (int nt = 0; nt < 4; ++nt)
#pragma unroll
                for (int q = 0; q < 4; ++q) {
                    float h = fast_tanh(acc[mt][nt][q] + bias[nt]);
                    acc[mt][nt][q] = h;
                    if (L != NSUB - 1)   // last layer's output stays in regs for final dot
                        sA[(wave * 64 + mt * 16 + g * 4 + q) * LDA + nt * 16 + r15] = f2bf(h);
                }
    }

    // ---- final: u[p] = h @ Wl + bl, reduced across the 16-lane group ----
    float wl[4];
#pragma unroll
    for (int nt = 0; nt < 4; ++nt) wl[nt] = sWl[nt * 16 + r15];

    float s[4][4];
#pragma unroll
    for (int mt = 0; mt < 4; ++mt)
#pragma unroll
        for (int q = 0; q < 4; ++q) {
            float v = acc[mt][0][q] * wl[0] + acc[mt][1][q] * wl[1]
                    + acc[mt][2][q] * wl[2] + acc[mt][3][q] * wl[3];
            v += __shfl_xor(v, 1);
            v += __shfl_xor(v, 2);
            v += __shfl_xor(v, 4);
            v += __shfl_xor(v, 8);
            s[mt][q] = v;
        }

    float u = 0.0f;
#pragma unroll
    for (int mt = 0; mt < 4; ++mt)
#pragma unroll
        for (int q = 0; q < 4; ++q)
            if (r15 == mt * 4 + q) u = s[mt][q];   // static-index select
    u += gbl[j];

    const int p = pbase + wave * 64 + (r15 >> 2) * 16 + g * 4 + (r15 & 3);
    upart[j * NP + p] = u * w_all[j * NP + p];
}

// ---------------- Reduce over j + Dirichlet ansatz (unchanged) ----------------
__global__ __launch_bounds__(256) void reduce_kernel(
    const float* __restrict__ x,
    const float* __restrict__ upart,
    float* __restrict__ out)
{
    const int p = blockIdx.x * 256 + threadIdx.x;
    float s = 0.0f;
#pragma unroll
    for (int j = 0; j < NJ; ++j) s += upart[j * NP + p];
    const float x0 = x[2 * p], x1 = x[2 * p + 1];
    const float pi = 3.14159265358979323846f;
    out[p] = s * sinf(pi * x0) * sinf(pi * x1);
}

extern "C" void kernel_launch(void* const* d_in, const int* in_sizes, int n_in,
                              void* d_out, int out_size, void* d_ws, size_t ws_size,
                              hipStream_t stream) {
    const float* x      = (const float*)d_in[0];
    const float* sub_W0 = (const float*)d_in[1];
    const float* sub_b0 = (const float*)d_in[2];
    const float* sub_Wh = (const float*)d_in[3];
    const float* sub_bh = (const float*)d_in[4];
    const float* sub_Wl = (const float*)d_in[5];
    const float* sub_bl = (const float*)d_in[6];
    const float* pou_W0 = (const float*)d_in[7];
    const float* pou_b0 = (const float*)d_in[8];
    const float* pou_Wh = (const float*)d_in[9];
    const float* pou_bh = (const float*)d_in[10];
    const float* pou_Wl = (const float*)d_in[11];
    const float* pou_bl = (const float*)d_in[12];

    float* w_all = (float*)d_ws;                   // [J][P] 4 MB
    float* upart = (float*)d_ws + (size_t)NJ * NP; // [J][P] 4 MB

    pou_kernel<<<NP / 256, 256, 0, stream>>>(x, pou_W0, pou_b0, pou_Wh, pou_bh,
                                             pou_Wl, pou_bl, w_all);

    dim3 g2(NP / 256, NJ);
    subnet_mfma_kernel<<<g2, 256, 0, stream>>>(x, sub_W0, sub_b0, sub_Wh, sub_bh,
                                               sub_Wl, sub_bl, w_all, upart);

    reduce_kernel<<<NP / 256, 256, 0, stream>>>(x, upart, (float*)d_out);
}

// Round 3
// 99.463 us; speedup vs baseline: 3.8036x; 1.5576x over previous
//
#include <hip/hip_runtime.h>
#include <math.h>

#define NP 65536
#define NJ 16
#define WID 64
#define HH 64
#define NPOU 4
#define NSUB 2

typedef __attribute__((ext_vector_type(8))) short short8;
typedef __attribute__((ext_vector_type(4))) float f32x4;
typedef __attribute__((ext_vector_type(4))) int int4v;

// swizzled LDS layout: 64 bf16 per row (128 B = 8 chunks of 16 B), chunk ^= row&7
#define CHUNK_US(row, chunk) ((((row) << 6)) + ((((chunk) ^ ((row) & 7))) << 3))
__device__ __forceinline__ int usIdx(int row, int col) {
    return ((row) << 6) + ((((col >> 3) ^ (row & 7))) << 3) + (col & 7);
}

__device__ __forceinline__ unsigned short f2bf(float f) {   // RNE (weights, one-time)
    unsigned u = __float_as_uint(f);
    u += 0x7FFFu + ((u >> 16) & 1u);
    return (unsigned short)(u >> 16);
}
__device__ __forceinline__ unsigned short rhu(float f) {    // round-half-up (hot path)
    return (unsigned short)((__float_as_uint(f) + 0x8000u) >> 16);
}
__device__ __forceinline__ unsigned pk2(float a, float b) { // pack 2 bf16: a->low, b->high
    unsigned ua = __float_as_uint(a) + 0x8000u;
    unsigned ub = __float_as_uint(b) + 0x8000u;
    return __builtin_amdgcn_perm(ub, ua, 0x07060302u);
}
__device__ __forceinline__ float bf2f(unsigned short s) {
    return __uint_as_float(((unsigned)s) << 16);
}
// tanh with pre-scaled argument: y = 2*z  ->  tanh(z) = 1 - 2/(e^y + 1)
__device__ __forceinline__ float tanh_pre(float y) {
    float e = __expf(y);
    return fmaf(-2.0f, __builtin_amdgcn_rcpf(e + 1.0f), 1.0f);
}

// ================= POU network via MFMA: w_all[j][p] = softmax_j(ResMLP(x)) =================
__global__ __launch_bounds__(256) void pou_mfma_kernel(
    const float* __restrict__ x,
    const float* __restrict__ W0, const float* __restrict__ b0,
    const float* __restrict__ Wh, const float* __restrict__ bh,
    const float* __restrict__ Wl, const float* __restrict__ bl,
    float* __restrict__ w_all)
{
    __shared__ unsigned short sA[4 * 64 * 64];          // per-wave trunk tiles (bf16, swizzled) 32KB
    __shared__ unsigned short sWhT[NPOU * 64 * 64];     // W^T per res layer (bf16, swizzled) 32KB
    __shared__ unsigned short sWlT[16 * 64];            // Wl^T [j][k] (bf16, swizzled) 2KB
    __shared__ float sW0a[HH], sW0b[HH], sB0[HH];
    __shared__ float sbh[NPOU * HH];
    __shared__ float sbl[NJ];

    const int tid  = threadIdx.x;
    const int wave = tid >> 6;
    const int lane = tid & 63;
    const int r15  = lane & 15;
    const int g    = lane >> 4;

    // ---- stage weights ----
    for (int idx = tid; idx < NPOU * HH * HH; idx += 256) {
        int r = idx >> 12, k = (idx >> 6) & 63, n = idx & 63;
        sWhT[r * 4096 + usIdx(n, k)] = f2bf(Wh[idx]);
    }
    for (int idx = tid; idx < HH * NJ; idx += 256) {
        int k = idx >> 4, j = idx & 15;
        sWlT[usIdx(j, k)] = f2bf(Wl[idx]);
    }
    if (tid < HH) { sW0a[tid] = W0[tid]; sW0b[tid] = W0[HH + tid]; sB0[tid] = b0[tid]; }
    for (int i = tid; i < NPOU * HH; i += 256) sbh[i] = bh[i];
    if (tid < NJ) sbl[tid] = bl[tid];
    __syncthreads();

    unsigned short* myA = &sA[wave * 4096];
    const int pbase = blockIdx.x * 256;

    // ---- L0: h = relu(x@W0 + b0), scalar per thread (thread = point = row lane) ----
    {
        const int p = pbase + tid;
        float2 xv = ((const float2*)x)[p];
        float v[HH];
#pragma unroll
        for (int c = 0; c < HH; ++c)
            v[c] = fmaxf(fmaf(xv.x, sW0a[c], fmaf(xv.y, sW0b[c], sB0[c])), 0.0f);
#pragma unroll
        for (int c = 0; c < 8; ++c) {
            int4v r;
            r.x = (int)pk2(v[8 * c + 0], v[8 * c + 1]);
            r.y = (int)pk2(v[8 * c + 2], v[8 * c + 3]);
            r.z = (int)pk2(v[8 * c + 4], v[8 * c + 5]);
            r.w = (int)pk2(v[8 * c + 6], v[8 * c + 7]);
            *(int4v*)&myA[CHUNK_US(lane, c)] = r;
        }
    }

    // ---- read trunk back in C-layout (f32 regs, quantized-consistent with sA) ----
    float trunk[4][4][4];
#pragma unroll
    for (int mt = 0; mt < 4; ++mt)
#pragma unroll
        for (int nt = 0; nt < 4; ++nt)
#pragma unroll
            for (int q = 0; q < 4; ++q)
                trunk[mt][nt][q] = bf2f(myA[usIdx(mt * 16 + g * 4 + q, nt * 16 + r15)]);

    // ---- residual relu blocks: trunk += relu(trunk_bf @ Wh[r] + bh[r]) ----
#pragma unroll 1
    for (int r = 0; r < NPOU; ++r) {
        const unsigned short* wt = &sWhT[r * 4096];
        short8 bfr[2][4];
#pragma unroll
        for (int kc = 0; kc < 2; ++kc)
#pragma unroll
            for (int nt = 0; nt < 4; ++nt)
                bfr[kc][nt] = *(const short8*)&wt[CHUNK_US(nt * 16 + r15, kc * 4 + g)];
        float bias[4];
#pragma unroll
        for (int nt = 0; nt < 4; ++nt) bias[nt] = sbh[r * HH + nt * 16 + r15];

#pragma unroll
        for (int mt = 0; mt < 4; ++mt) {
            short8 a0 = *(const short8*)&myA[CHUNK_US(mt * 16 + r15, g)];
            short8 a1 = *(const short8*)&myA[CHUNK_US(mt * 16 + r15, 4 + g)];
            f32x4 acc[4];
#pragma unroll
            for (int nt = 0; nt < 4; ++nt) {
                acc[nt] = (f32x4)(0.0f);
                acc[nt] = __builtin_amdgcn_mfma_f32_16x16x32_bf16(a0, bfr[0][nt], acc[nt], 0, 0, 0);
                acc[nt] = __builtin_amdgcn_mfma_f32_16x16x32_bf16(a1, bfr[1][nt], acc[nt], 0, 0, 0);
            }
#pragma unroll
            for (int nt = 0; nt < 4; ++nt)
#pragma unroll
                for (int q = 0; q < 4; ++q) {
                    float t = trunk[mt][nt][q] + fmaxf(acc[nt][q] + bias[nt], 0.0f);
                    trunk[mt][nt][q] = t;
                    myA[usIdx(mt * 16 + g * 4 + q, nt * 16 + r15)] = rhu(t);
                }
        }
    }

    // ---- logits = trunk_bf @ Wl + bl via MFMA (N = 16 = J), softmax over r15 lanes ----
    short8 bw0 = *(const short8*)&sWlT[CHUNK_US(r15, g)];
    short8 bw1 = *(const short8*)&sWlT[CHUNK_US(r15, 4 + g)];
    float lg[4][4], mx[4][4];
#pragma unroll
    for (int mt = 0; mt < 4; ++mt) {
        short8 a0 = *(const short8*)&myA[CHUNK_US(mt * 16 + r15, g)];
        short8 a1 = *(const short8*)&myA[CHUNK_US(mt * 16 + r15, 4 + g)];
        f32x4 acc = (f32x4)(0.0f);
        acc = __builtin_amdgcn_mfma_f32_16x16x32_bf16(a0, bw0, acc, 0, 0, 0);
        acc = __builtin_amdgcn_mfma_f32_16x16x32_bf16(a1, bw1, acc, 0, 0, 0);
#pragma unroll
        for (int q = 0; q < 4; ++q) { lg[mt][q] = acc[q] + sbl[r15]; mx[mt][q] = lg[mt][q]; }
    }
#pragma unroll
    for (int mask = 1; mask < 16; mask <<= 1)
#pragma unroll
        for (int mt = 0; mt < 4; ++mt)
#pragma unroll
            for (int q = 0; q < 4; ++q) mx[mt][q] = fmaxf(mx[mt][q], __shfl_xor(mx[mt][q], mask));
    float ev[4][4], sm[4][4];
#pragma unroll
    for (int mt = 0; mt < 4; ++mt)
#pragma unroll
        for (int q = 0; q < 4; ++q) { ev[mt][q] = __expf(lg[mt][q] - mx[mt][q]); sm[mt][q] = ev[mt][q]; }
#pragma unroll
    for (int mask = 1; mask < 16; mask <<= 1)
#pragma unroll
        for (int mt = 0; mt < 4; ++mt)
#pragma unroll
            for (int q = 0; q < 4; ++q) sm[mt][q] += __shfl_xor(sm[mt][q], mask);
#pragma unroll
    for (int mt = 0; mt < 4; ++mt)
#pragma unroll
        for (int q = 0; q < 4; ++q) {
            const int p = pbase + wave * 64 + mt * 16 + g * 4 + q;
            w_all[r15 * NP + p] = ev[mt][q] * __builtin_amdgcn_rcpf(sm[mt][q]);
        }
}

// ================= Subnet j via MFMA (tanh scale folded into weights) =================
__global__ __launch_bounds__(256) void subnet_mfma_kernel(
    const float* __restrict__ x,
    const float* __restrict__ gW0, const float* __restrict__ gb0,
    const float* __restrict__ gWh, const float* __restrict__ gbh,
    const float* __restrict__ gWl, const float* __restrict__ gbl,
    const float* __restrict__ w_all,
    float* __restrict__ upart)
{
    __shared__ unsigned short sA[4 * 64 * 64];        // per-wave activations (bf16, swizzled) 32KB
    __shared__ unsigned short sWt[NSUB * 64 * 64];    // 2*W^T (bf16, swizzled) 16KB
    __shared__ float sW0a[WID], sW0b[WID], sB0[WID];  // folded: 4*W0, 2*(b0-w0-w1)
    __shared__ float sbh[NSUB * WID];                 // 2*bh
    __shared__ float sWl[WID];
    __shared__ float sbl1;

    const int tid  = threadIdx.x;
    const int j    = blockIdx.y;
    const int wave = tid >> 6;
    const int lane = tid & 63;
    const int r15  = lane & 15;
    const int g    = lane >> 4;

    // ---- stage weights (scale folding; RNE for bf16) ----
    {
        const float* src = gWh + j * (NSUB * WID * WID);
        for (int idx = tid; idx < NSUB * WID * WID; idx += 256) {
            int L = idx >> 12, k = (idx >> 6) & 63, n = idx & 63;
            sWt[L * 4096 + usIdx(n, k)] = f2bf(2.0f * src[idx]);
        }
        if (tid < WID) {
            float w0 = gW0[j * 2 * WID + tid], w1 = gW0[j * 2 * WID + WID + tid];
            sW0a[tid] = 4.0f * w0;
            sW0b[tid] = 4.0f * w1;
            sB0[tid]  = 2.0f * (gb0[j * WID + tid] - w0 - w1);
        }
        if (tid < NSUB * WID) sbh[tid] = 2.0f * gbh[j * NSUB * WID + tid];
        if (tid < WID) sWl[tid] = gWl[j * WID + tid];
        if (tid == 0) sbl1 = gbl[j];
    }
    __syncthreads();

    unsigned short* myA = &sA[wave * 4096];
    const int pbase = blockIdx.x * 256;

    // ---- L0: tanh((2x-1)@W0*2 + ...) folded; thread = point = row lane ----
    {
        const int p = pbase + tid;
        float2 xv = ((const float2*)x)[p];
        float v[WID];
#pragma unroll
        for (int c = 0; c < WID; ++c)
            v[c] = tanh_pre(fmaf(xv.x, sW0a[c], fmaf(xv.y, sW0b[c], sB0[c])));
#pragma unroll
        for (int c = 0; c < 8; ++c) {
            int4v r;
            r.x = (int)pk2(v[8 * c + 0], v[8 * c + 1]);
            r.y = (int)pk2(v[8 * c + 2], v[8 * c + 3]);
            r.z = (int)pk2(v[8 * c + 4], v[8 * c + 5]);
            r.w = (int)pk2(v[8 * c + 6], v[8 * c + 7]);
            *(int4v*)&myA[CHUNK_US(lane, c)] = r;
        }
    }

    float hk[4][4][4];   // last hidden layer's tanh outputs (C-layout)

    // ---- hidden layers via MFMA ----
#pragma unroll
    for (int L = 0; L < NSUB; ++L) {
        const unsigned short* wt = &sWt[L * 4096];
        short8 bfr[2][4];
#pragma unroll
        for (int kc = 0; kc < 2; ++kc)
#pragma unroll
            for (int nt = 0; nt < 4; ++nt)
                bfr[kc][nt] = *(const short8*)&wt[CHUNK_US(nt * 16 + r15, kc * 4 + g)];
        float bias[4];
#pragma unroll
        for (int nt = 0; nt < 4; ++nt) bias[nt] = sbh[L * WID + nt * 16 + r15];

#pragma unroll
        for (int mt = 0; mt < 4; ++mt) {
            short8 a0 = *(const short8*)&myA[CHUNK_US(mt * 16 + r15, g)];
            short8 a1 = *(const short8*)&myA[CHUNK_US(mt * 16 + r15, 4 + g)];
            f32x4 acc[4];
#pragma unroll
            for (int nt = 0; nt < 4; ++nt) {
                acc[nt] = (f32x4)(0.0f);
                acc[nt] = __builtin_amdgcn_mfma_f32_16x16x32_bf16(a0, bfr[0][nt], acc[nt], 0, 0, 0);
                acc[nt] = __builtin_amdgcn_mfma_f32_16x16x32_bf16(a1, bfr[1][nt], acc[nt], 0, 0, 0);
            }
#pragma unroll
            for (int nt = 0; nt < 4; ++nt)
#pragma unroll
                for (int q = 0; q < 4; ++q) {
                    float h = tanh_pre(acc[nt][q] + bias[nt]);
                    if (L == 0)
                        myA[usIdx(mt * 16 + g * 4 + q, nt * 16 + r15)] = rhu(h);
                    else
                        hk[mt][nt][q] = h;
                }
        }
    }

    // ---- final: u = h @ Wl + bl, 16-lane butterfly reduce ----
    float wl[4];
#pragma unroll
    for (int nt = 0; nt < 4; ++nt) wl[nt] = sWl[nt * 16 + r15];

    float s[4][4];
#pragma unroll
    for (int mt = 0; mt < 4; ++mt)
#pragma unroll
        for (int q = 0; q < 4; ++q) {
            float v = hk[mt][0][q] * wl[0] + hk[mt][1][q] * wl[1]
                    + hk[mt][2][q] * wl[2] + hk[mt][3][q] * wl[3];
            v += __shfl_xor(v, 1);
            v += __shfl_xor(v, 2);
            v += __shfl_xor(v, 4);
            v += __shfl_xor(v, 8);
            s[mt][q] = v;
        }

    float u = 0.0f;
#pragma unroll
    for (int mt = 0; mt < 4; ++mt)
#pragma unroll
        for (int q = 0; q < 4; ++q)
            if (r15 == mt * 4 + q) u = s[mt][q];
    u += sbl1;

    const int p = pbase + wave * 64 + (r15 >> 2) * 16 + g * 4 + (r15 & 3);
    upart[j * NP + p] = u * w_all[j * NP + p];
}

// ================= Reduce over j + Dirichlet ansatz (hw v_sin) =================
__global__ __launch_bounds__(256) void reduce_kernel(
    const float* __restrict__ x,
    const float* __restrict__ upart,
    float* __restrict__ out)
{
    const int p = blockIdx.x * 256 + threadIdx.x;
    float s = 0.0f;
#pragma unroll
    for (int j = 0; j < NJ; ++j) s += upart[j * NP + p];
    float2 xv = ((const float2*)x)[p];
    // sin(pi*x) = v_sin(x/2) (v_sin takes revolutions); x in [0,1] -> no range reduction
    float s0 = __builtin_amdgcn_sinf(xv.x * 0.5f);
    float s1 = __builtin_amdgcn_sinf(xv.y * 0.5f);
    out[p] = s * s0 * s1;
}

extern "C" void kernel_launch(void* const* d_in, const int* in_sizes, int n_in,
                              void* d_out, int out_size, void* d_ws, size_t ws_size,
                              hipStream_t stream) {
    const float* x      = (const float*)d_in[0];
    const float* sub_W0 = (const float*)d_in[1];
    const float* sub_b0 = (const float*)d_in[2];
    const float* sub_Wh = (const float*)d_in[3];
    const float* sub_bh = (const float*)d_in[4];
    const float* sub_Wl = (const float*)d_in[5];
    const float* sub_bl = (const float*)d_in[6];
    const float* pou_W0 = (const float*)d_in[7];
    const float* pou_b0 = (const float*)d_in[8];
    const float* pou_Wh = (const float*)d_in[9];
    const float* pou_bh = (const float*)d_in[10];
    const float* pou_Wl = (const float*)d_in[11];
    const float* pou_bl = (const float*)d_in[12];

    float* w_all = (float*)d_ws;                   // [J][P] 4 MB
    float* upart = (float*)d_ws + (size_t)NJ * NP; // [J][P] 4 MB

    pou_mfma_kernel<<<NP / 256, 256, 0, stream>>>(x, pou_W0, pou_b0, pou_Wh, pou_bh,
                                                  pou_Wl, pou_bl, w_all);

    dim3 g2(NP / 256, NJ);
    subnet_mfma_kernel<<<g2, 256, 0, stream>>>(x, sub_W0, sub_b0, sub_Wh, sub_bh,
                                               sub_Wl, sub_bl, w_all, upart);

    reduce_kernel<<<NP / 256, 256, 0, stream>>>(x, upart, (float*)d_out);
}

// Round 4
// 87.920 us; speedup vs baseline: 4.3030x; 1.1313x over previous
//
#include <hip/hip_runtime.h>
#include <math.h>

#define NP 65536
#define NJ 16
#define WID 64
#define HH 64
#define NPOU 4
#define NSUB 2
#define L2E2 2.8853900817779268f   // 2*log2(e)

typedef __attribute__((ext_vector_type(8))) short short8;
typedef __attribute__((ext_vector_type(4))) float f32x4;
typedef __attribute__((ext_vector_type(4))) int int4v;

// swizzled LDS layout: 64 bf16 per row (128 B = 8 chunks of 16 B), chunk ^= row&7
#define CHUNK_US(row, chunk) ((((row) << 6)) + ((((chunk) ^ ((row) & 7))) << 3))
__device__ __forceinline__ int usIdx(int row, int col) {
    return ((row) << 6) + ((((col >> 3) ^ (row & 7))) << 3) + (col & 7);
}

__device__ __forceinline__ unsigned short f2bf(float f) {   // RNE (weights, one-time)
    unsigned u = __float_as_uint(f);
    u += 0x7FFFu + ((u >> 16) & 1u);
    return (unsigned short)(u >> 16);
}
__device__ __forceinline__ unsigned short rhu(float f) {
    return (unsigned short)((__float_as_uint(f) + 0x8000u) >> 16);
}
__device__ __forceinline__ unsigned pk2(float a, float b) { // pack 2 bf16: a->low, b->high
    unsigned ua = __float_as_uint(a) + 0x8000u;
    unsigned ub = __float_as_uint(b) + 0x8000u;
    return __builtin_amdgcn_perm(ub, ua, 0x07060302u);
}
__device__ __forceinline__ float bf2f(unsigned short s) {
    return __uint_as_float(((unsigned)s) << 16);
}
// tanh with argument pre-scaled by 2*log2e: tanh(z) = 1 - 2/(2^(y)+1), y = 2*log2e*z
__device__ __forceinline__ float tanh2(float y) {
    float e = __builtin_amdgcn_exp2f(y);
    return fmaf(-2.0f, __builtin_amdgcn_rcpf(e + 1.0f), 1.0f);
}
__device__ __forceinline__ short8 mk8(unsigned a, unsigned b, unsigned c, unsigned d) {
    int4v t; t.x = (int)a; t.y = (int)b; t.z = (int)c; t.w = (int)d;
    return __builtin_bit_cast(short8, t);
}

// ================= POU network via MFMA (unchanged from passing R3) =================
__global__ __launch_bounds__(256) void pou_mfma_kernel(
    const float* __restrict__ x,
    const float* __restrict__ W0, const float* __restrict__ b0,
    const float* __restrict__ Wh, const float* __restrict__ bh,
    const float* __restrict__ Wl, const float* __restrict__ bl,
    float* __restrict__ w_all)
{
    __shared__ unsigned short sA[4 * 64 * 64];
    __shared__ unsigned short sWhT[NPOU * 64 * 64];
    __shared__ unsigned short sWlT[16 * 64];
    __shared__ float sW0a[HH], sW0b[HH], sB0[HH];
    __shared__ float sbh[NPOU * HH];
    __shared__ float sbl[NJ];

    const int tid  = threadIdx.x;
    const int wave = tid >> 6;
    const int lane = tid & 63;
    const int r15  = lane & 15;
    const int g    = lane >> 4;

    for (int idx = tid; idx < NPOU * HH * HH; idx += 256) {
        int r = idx >> 12, k = (idx >> 6) & 63, n = idx & 63;
        sWhT[r * 4096 + usIdx(n, k)] = f2bf(Wh[idx]);
    }
    for (int idx = tid; idx < HH * NJ; idx += 256) {
        int k = idx >> 4, j = idx & 15;
        sWlT[usIdx(j, k)] = f2bf(Wl[idx]);
    }
    if (tid < HH) { sW0a[tid] = W0[tid]; sW0b[tid] = W0[HH + tid]; sB0[tid] = b0[tid]; }
    for (int i = tid; i < NPOU * HH; i += 256) sbh[i] = bh[i];
    if (tid < NJ) sbl[tid] = bl[tid];
    __syncthreads();

    unsigned short* myA = &sA[wave * 4096];
    const int pbase = blockIdx.x * 256;

    {
        const int p = pbase + tid;
        float2 xv = ((const float2*)x)[p];
        float v[HH];
#pragma unroll
        for (int c = 0; c < HH; ++c)
            v[c] = fmaxf(fmaf(xv.x, sW0a[c], fmaf(xv.y, sW0b[c], sB0[c])), 0.0f);
#pragma unroll
        for (int c = 0; c < 8; ++c) {
            int4v r;
            r.x = (int)pk2(v[8 * c + 0], v[8 * c + 1]);
            r.y = (int)pk2(v[8 * c + 2], v[8 * c + 3]);
            r.z = (int)pk2(v[8 * c + 4], v[8 * c + 5]);
            r.w = (int)pk2(v[8 * c + 6], v[8 * c + 7]);
            *(int4v*)&myA[CHUNK_US(lane, c)] = r;
        }
    }

    float trunk[4][4][4];
#pragma unroll
    for (int mt = 0; mt < 4; ++mt)
#pragma unroll
        for (int nt = 0; nt < 4; ++nt)
#pragma unroll
            for (int q = 0; q < 4; ++q)
                trunk[mt][nt][q] = bf2f(myA[usIdx(mt * 16 + g * 4 + q, nt * 16 + r15)]);

#pragma unroll 1
    for (int r = 0; r < NPOU; ++r) {
        const unsigned short* wt = &sWhT[r * 4096];
        short8 bfr[2][4];
#pragma unroll
        for (int kc = 0; kc < 2; ++kc)
#pragma unroll
            for (int nt = 0; nt < 4; ++nt)
                bfr[kc][nt] = *(const short8*)&wt[CHUNK_US(nt * 16 + r15, kc * 4 + g)];
        float bias[4];
#pragma unroll
        for (int nt = 0; nt < 4; ++nt) bias[nt] = sbh[r * HH + nt * 16 + r15];

#pragma unroll
        for (int mt = 0; mt < 4; ++mt) {
            short8 a0 = *(const short8*)&myA[CHUNK_US(mt * 16 + r15, g)];
            short8 a1 = *(const short8*)&myA[CHUNK_US(mt * 16 + r15, 4 + g)];
            f32x4 acc[4];
#pragma unroll
            for (int nt = 0; nt < 4; ++nt) {
                acc[nt] = (f32x4)(0.0f);
                acc[nt] = __builtin_amdgcn_mfma_f32_16x16x32_bf16(a0, bfr[0][nt], acc[nt], 0, 0, 0);
                acc[nt] = __builtin_amdgcn_mfma_f32_16x16x32_bf16(a1, bfr[1][nt], acc[nt], 0, 0, 0);
            }
#pragma unroll
            for (int nt = 0; nt < 4; ++nt)
#pragma unroll
                for (int q = 0; q < 4; ++q) {
                    float t = trunk[mt][nt][q] + fmaxf(acc[nt][q] + bias[nt], 0.0f);
                    trunk[mt][nt][q] = t;
                    myA[usIdx(mt * 16 + g * 4 + q, nt * 16 + r15)] = rhu(t);
                }
        }
    }

    short8 bw0 = *(const short8*)&sWlT[CHUNK_US(r15, g)];
    short8 bw1 = *(const short8*)&sWlT[CHUNK_US(r15, 4 + g)];
    float lg[4][4], mx[4][4];
#pragma unroll
    for (int mt = 0; mt < 4; ++mt) {
        short8 a0 = *(const short8*)&myA[CHUNK_US(mt * 16 + r15, g)];
        short8 a1 = *(const short8*)&myA[CHUNK_US(mt * 16 + r15, 4 + g)];
        f32x4 acc = (f32x4)(0.0f);
        acc = __builtin_amdgcn_mfma_f32_16x16x32_bf16(a0, bw0, acc, 0, 0, 0);
        acc = __builtin_amdgcn_mfma_f32_16x16x32_bf16(a1, bw1, acc, 0, 0, 0);
#pragma unroll
        for (int q = 0; q < 4; ++q) { lg[mt][q] = acc[q] + sbl[r15]; mx[mt][q] = lg[mt][q]; }
    }
#pragma unroll
    for (int mask = 1; mask < 16; mask <<= 1)
#pragma unroll
        for (int mt = 0; mt < 4; ++mt)
#pragma unroll
            for (int q = 0; q < 4; ++q) mx[mt][q] = fmaxf(mx[mt][q], __shfl_xor(mx[mt][q], mask));
    float ev[4][4], sm[4][4];
#pragma unroll
    for (int mt = 0; mt < 4; ++mt)
#pragma unroll
        for (int q = 0; q < 4; ++q) { ev[mt][q] = __expf(lg[mt][q] - mx[mt][q]); sm[mt][q] = ev[mt][q]; }
#pragma unroll
    for (int mask = 1; mask < 16; mask <<= 1)
#pragma unroll
        for (int mt = 0; mt < 4; ++mt)
#pragma unroll
            for (int q = 0; q < 4; ++q) sm[mt][q] += __shfl_xor(sm[mt][q], mask);
#pragma unroll
    for (int mt = 0; mt < 4; ++mt)
#pragma unroll
        for (int q = 0; q < 4; ++q) {
            const int p = pbase + wave * 64 + mt * 16 + g * 4 + q;
            w_all[r15 * NP + p] = ev[mt][q] * __builtin_amdgcn_rcpf(sm[mt][q]);
        }
}

// ======== Subnet j, transposed chain: H^T_{L+1} = W^T_L * H^T_L, all in-register ========
__global__ __launch_bounds__(256) void subnet_mfma_kernel(
    const float* __restrict__ x,
    const float* __restrict__ gW0, const float* __restrict__ gb0,
    const float* __restrict__ gWh, const float* __restrict__ gbh,
    const float* __restrict__ gWl, const float* __restrict__ gbl,
    const float* __restrict__ w_all,
    float* __restrict__ upart)
{
    __shared__ __align__(16) unsigned short sWt[NSUB * 64 * 64]; // W^T [out][in] bf16 swz, *2*l2e
    __shared__ __align__(16) float sW0a[WID], sW0b[WID], sB0[WID]; // folded, *l2e scales
    __shared__ __align__(16) float sbh[NSUB * WID];                // *2*l2e
    __shared__ __align__(16) float sWl[WID];
    __shared__ float sbl1v;

    const int tid  = threadIdx.x;
    const int j    = blockIdx.y;
    const int wave = tid >> 6;
    const int lane = tid & 63;
    const int c    = lane & 15;
    const int g    = lane >> 4;

    // ---- stage weights (scale folding; RNE bf16) ----
    {
        const float* src = gWh + j * (NSUB * WID * WID);
        for (int idx = tid; idx < NSUB * WID * WID; idx += 256) {
            int L = idx >> 12, k = (idx >> 6) & 63, n = idx & 63;
            sWt[L * 4096 + usIdx(n, k)] = f2bf(L2E2 * src[idx]);
        }
        if (tid < WID) {
            float w0 = gW0[j * 2 * WID + tid], w1 = gW0[j * 2 * WID + WID + tid];
            sW0a[tid] = 2.0f * L2E2 * w0;
            sW0b[tid] = 2.0f * L2E2 * w1;
            sB0[tid]  = L2E2 * (gb0[j * WID + tid] - w0 - w1);
        }
        if (tid < NSUB * WID) sbh[tid] = L2E2 * gbh[j * NSUB * WID + tid];
        if (tid < WID) sWl[tid] = gWl[j * WID + tid];
        if (tid == 0) sbl1v = gbl[j];
    }
    __syncthreads();

    const int pb = blockIdx.x * 256 + wave * 64;

    // ---- L0 directly in B-frag layout: lane computes feats {kc*32+8g+e} for 4 points ----
    short8 bf[2][4];   // [kc][nt]: B-frag of H^T (k = feature, col = point)
    {
        float xs0[4], xs1[4];
#pragma unroll
        for (int nt = 0; nt < 4; ++nt) {
            float2 xv = ((const float2*)x)[pb + nt * 16 + c];
            xs0[nt] = xv.x; xs1[nt] = xv.y;
        }
        f32x4 wa[2][2], wb[2][2], bb[2][2];
#pragma unroll
        for (int kc = 0; kc < 2; ++kc)
#pragma unroll
            for (int hf = 0; hf < 2; ++hf) {
                wa[kc][hf] = *(const f32x4*)&sW0a[kc * 32 + 8 * g + 4 * hf];
                wb[kc][hf] = *(const f32x4*)&sW0b[kc * 32 + 8 * g + 4 * hf];
                bb[kc][hf] = *(const f32x4*)&sB0 [kc * 32 + 8 * g + 4 * hf];
            }
        unsigned t[2][4][4];
#pragma unroll
        for (int kc = 0; kc < 2; ++kc)
#pragma unroll
            for (int pr = 0; pr < 4; ++pr) {
                const int h0 = pr >> 1, e0 = (2 * pr) & 3, e1 = e0 + 1;
#pragma unroll
                for (int nt = 0; nt < 4; ++nt) {
                    float v0 = tanh2(fmaf(xs0[nt], wa[kc][h0][e0], fmaf(xs1[nt], wb[kc][h0][e0], bb[kc][h0][e0])));
                    float v1 = tanh2(fmaf(xs0[nt], wa[kc][h0][e1], fmaf(xs1[nt], wb[kc][h0][e1], bb[kc][h0][e1])));
                    t[kc][nt][pr] = pk2(v0, v1);
                }
            }
#pragma unroll
        for (int kc = 0; kc < 2; ++kc)
#pragma unroll
            for (int nt = 0; nt < 4; ++nt)
                bf[kc][nt] = mk8(t[kc][nt][0], t[kc][nt][1], t[kc][nt][2], t[kc][nt][3]);
    }

    float red[4];   // per-nt final partial dots
#pragma unroll
    for (int nt = 0; nt < 4; ++nt) red[nt] = 0.0f;

    // ---- hidden layers: D[out][pt] = W^T (A-frag) * H^T (B-frag) ----
#pragma unroll
    for (int L = 0; L < NSUB; ++L) {
        const unsigned short* wt = &sWt[L * 4096];
        short8 aw[4][2];
#pragma unroll
        for (int mt = 0; mt < 4; ++mt)
#pragma unroll
            for (int kc = 0; kc < 2; ++kc)
                aw[mt][kc] = *(const short8*)&wt[CHUNK_US(mt * 16 + c, kc * 4 + g)];
        f32x4 bias[4];
#pragma unroll
        for (int mt = 0; mt < 4; ++mt)
            bias[mt] = *(const f32x4*)&sbh[L * 64 + mt * 16 + 4 * g];

#pragma unroll
        for (int nt = 0; nt < 4; ++nt) {
            f32x4 acc[4];
#pragma unroll
            for (int mt = 0; mt < 4; ++mt) acc[mt] = bias[mt];   // bias as C-init
#pragma unroll
            for (int mt = 0; mt < 4; ++mt) {
                acc[mt] = __builtin_amdgcn_mfma_f32_16x16x32_bf16(aw[mt][0], bf[0][nt], acc[mt], 0, 0, 0);
                acc[mt] = __builtin_amdgcn_mfma_f32_16x16x32_bf16(aw[mt][1], bf[1][nt], acc[mt], 0, 0, 0);
            }

            if (L < NSUB - 1) {
                float h[4][4];
#pragma unroll
                for (int mt = 0; mt < 4; ++mt)
#pragma unroll
                    for (int q = 0; q < 4; ++q) h[mt][q] = tanh2(acc[mt][q]);
                // in-register C-layout -> B-frag transform (overwrite bf[*][nt])
#pragma unroll
                for (int kn = 0; kn < 2; ++kn) {
                    unsigned A0 = pk2(h[2 * kn][0],     h[2 * kn][1]);
                    unsigned A1 = pk2(h[2 * kn][2],     h[2 * kn][3]);
                    unsigned B0 = pk2(h[2 * kn + 1][0], h[2 * kn + 1][1]);
                    unsigned B1 = pk2(h[2 * kn + 1][2], h[2 * kn + 1][3]);
                    asm("v_permlane32_swap_b32 %0, %1" : "+v"(A0), "+v"(B0));
                    asm("v_permlane16_swap_b32 %0, %1" : "+v"(A0), "+v"(B0));
                    asm("v_permlane32_swap_b32 %0, %1" : "+v"(A1), "+v"(B1));
                    asm("v_permlane16_swap_b32 %0, %1" : "+v"(A1), "+v"(B1));
                    bf[kn][nt] = mk8(A0, A1, B0, B1);
                }
            } else {
                // last hidden layer: tanh then dot with Wl rows held per lane
#pragma unroll
                for (int mt = 0; mt < 4; ++mt) {
                    f32x4 wlv = *(const f32x4*)&sWl[mt * 16 + 4 * g];
#pragma unroll
                    for (int q = 0; q < 4; ++q)
                        red[nt] = fmaf(tanh2(acc[mt][q]), wlv[q], red[nt]);
                }
            }
        }
    }

    // ---- reduce over g-lane groups (sum of 16 out-rows per lane already in red) ----
#pragma unroll
    for (int nt = 0; nt < 4; ++nt) {
        red[nt] += __shfl_xor(red[nt], 16);
        red[nt] += __shfl_xor(red[nt], 32);
    }
    float u = (g & 1) ? ((g & 2) ? red[3] : red[1]) : ((g & 2) ? red[2] : red[0]);
    u += sbl1v;

    const int p = pb + lane;
    upart[j * NP + p] = u * w_all[j * NP + p];
}

// ================= Reduce over j + Dirichlet ansatz (float4) =================
__global__ __launch_bounds__(256) void reduce_kernel(
    const float* __restrict__ x,
    const float* __restrict__ upart,
    float* __restrict__ out)
{
    const int p4 = blockIdx.x * 256 + threadIdx.x;   // index of float4 group
    f32x4 s = (f32x4)(0.0f);
#pragma unroll
    for (int j = 0; j < NJ; ++j) s += *(const f32x4*)&upart[j * NP + 4 * p4];
    f32x4 xa = ((const f32x4*)x)[2 * p4];       // pts 0,1: (x0,y0,x1,y1)
    f32x4 xb = ((const f32x4*)x)[2 * p4 + 1];   // pts 2,3
    f32x4 o;
    o.x = s.x * __builtin_amdgcn_sinf(xa.x * 0.5f) * __builtin_amdgcn_sinf(xa.y * 0.5f);
    o.y = s.y * __builtin_amdgcn_sinf(xa.z * 0.5f) * __builtin_amdgcn_sinf(xa.w * 0.5f);
    o.z = s.z * __builtin_amdgcn_sinf(xb.x * 0.5f) * __builtin_amdgcn_sinf(xb.y * 0.5f);
    o.w = s.w * __builtin_amdgcn_sinf(xb.z * 0.5f) * __builtin_amdgcn_sinf(xb.w * 0.5f);
    *(f32x4*)&out[4 * p4] = o;
}

extern "C" void kernel_launch(void* const* d_in, const int* in_sizes, int n_in,
                              void* d_out, int out_size, void* d_ws, size_t ws_size,
                              hipStream_t stream) {
    const float* x      = (const float*)d_in[0];
    const float* sub_W0 = (const float*)d_in[1];
    const float* sub_b0 = (const float*)d_in[2];
    const float* sub_Wh = (const float*)d_in[3];
    const float* sub_bh = (const float*)d_in[4];
    const float* sub_Wl = (const float*)d_in[5];
    const float* sub_bl = (const float*)d_in[6];
    const float* pou_W0 = (const float*)d_in[7];
    const float* pou_b0 = (const float*)d_in[8];
    const float* pou_Wh = (const float*)d_in[9];
    const float* pou_bh = (const float*)d_in[10];
    const float* pou_Wl = (const float*)d_in[11];
    const float* pou_bl = (const float*)d_in[12];

    float* w_all = (float*)d_ws;                   // [J][P] 4 MB
    float* upart = (float*)d_ws + (size_t)NJ * NP; // [J][P] 4 MB

    pou_mfma_kernel<<<NP / 256, 256, 0, stream>>>(x, pou_W0, pou_b0, pou_Wh, pou_bh,
                                                  pou_Wl, pou_bl, w_all);

    dim3 g2(NP / 256, NJ);
    subnet_mfma_kernel<<<g2, 256, 0, stream>>>(x, sub_W0, sub_b0, sub_Wh, sub_bh,
                                               sub_Wl, sub_bl, w_all, upart);

    reduce_kernel<<<NP / 1024, 256, 0, stream>>>(x, upart, (float*)d_out);
}